// Round 1
// baseline (106.070 us; speedup 1.0000x reference)
//
#include <hip/hip_runtime.h>

// Head: fused QKV projection + causal attention, MI355X (gfx950)
// B=512, T=256, C=384, D=64. fp32 in/out, bf16 MFMA compute.

typedef short s16x8 __attribute__((ext_vector_type(8)));
typedef float f32x4 __attribute__((ext_vector_type(4)));
typedef unsigned short u16;

__device__ __forceinline__ u16 f2bf(float f) {
  unsigned u = __builtin_bit_cast(unsigned, f);
  u = (u + 0x7fffu + ((u >> 16) & 1u)) >> 16;   // RNE
  return (u16)u;
}

#define MFMA16 __builtin_amdgcn_mfma_f32_16x16x32_bf16

// ---------------------------------------------------------------------------
// Kernel 1: QKV projection. x[131072][384] f32 -> Q,K,V bf16 [512*256][64].
// BM=128 rows/block, N=192 (Q|K|V), BK=64, 4 waves (2x2 wave grid, 64x96 each).
// LDS rows are 128B; XOR-swizzle 16B slots with (row&7) to avoid bank conflicts.
// ---------------------------------------------------------------------------
__global__ __launch_bounds__(256) void qkv_kernel(
    const float* __restrict__ x,
    const float* __restrict__ WQ, const float* __restrict__ WK,
    const float* __restrict__ WV,
    u16* __restrict__ Qo, u16* __restrict__ Ko, u16* __restrict__ Vo)
{
  __shared__ char smem[128*64*2 + 192*64*2];   // xs 16KB | wsm 24KB
  char* xs  = smem;
  char* wsm = smem + 128*64*2;

  const int tid = threadIdx.x;
  const int l  = tid & 63;
  const int w  = tid >> 6;
  const int wm = w >> 1, wn = w & 1;
  const int g  = l >> 4, li = l & 15;
  const long mbase = (long)blockIdx.x * 128;

  f32x4 acc[4][6];
#pragma unroll
  for (int mi = 0; mi < 4; ++mi)
#pragma unroll
    for (int nt = 0; nt < 6; ++nt)
      acc[mi][nt] = (f32x4){0.f, 0.f, 0.f, 0.f};

  for (int kt = 0; kt < 6; ++kt) {
    __syncthreads();
    // ---- stage x tile [128][64] f32 -> bf16, swizzled ----
#pragma unroll
    for (int i = 0; i < 4; ++i) {
      int id = tid + 256 * i;              // 1024 chunks of 8 elems
      int row = id >> 3, slot = id & 7;
      const float4* src = reinterpret_cast<const float4*>(
          x + (mbase + row) * 384 + kt * 64 + slot * 8);
      float4 a = src[0], b = src[1];
      s16x8 h;
      h[0] = (short)f2bf(a.x); h[1] = (short)f2bf(a.y);
      h[2] = (short)f2bf(a.z); h[3] = (short)f2bf(a.w);
      h[4] = (short)f2bf(b.x); h[5] = (short)f2bf(b.y);
      h[6] = (short)f2bf(b.z); h[7] = (short)f2bf(b.w);
      *reinterpret_cast<s16x8*>(xs + row * 128 + ((slot ^ (row & 7)) << 4)) = h;
    }
    // ---- stage W tile [192][64] f32 -> bf16, swizzled (L2-resident source) ----
#pragma unroll
    for (int i = 0; i < 6; ++i) {
      int id = tid + 256 * i;              // 1536 chunks
      int row = id >> 3, slot = id & 7;
      const float* wsrc = (row < 64) ? (WQ + row * 384)
                         : (row < 128) ? (WK + (row - 64) * 384)
                                       : (WV + (row - 128) * 384);
      const float4* src = reinterpret_cast<const float4*>(wsrc + kt * 64 + slot * 8);
      float4 a = src[0], b = src[1];
      s16x8 h;
      h[0] = (short)f2bf(a.x); h[1] = (short)f2bf(a.y);
      h[2] = (short)f2bf(a.z); h[3] = (short)f2bf(a.w);
      h[4] = (short)f2bf(b.x); h[5] = (short)f2bf(b.y);
      h[6] = (short)f2bf(b.z); h[7] = (short)f2bf(b.w);
      *reinterpret_cast<s16x8*>(wsm + row * 128 + ((slot ^ (row & 7)) << 4)) = h;
    }
    __syncthreads();
    // ---- compute: 2 MFMA-K substeps of 32 ----
#pragma unroll
    for (int kk = 0; kk < 2; ++kk) {
      s16x8 bfrag[6];
#pragma unroll
      for (int nt = 0; nt < 6; ++nt) {
        int rb = wn * 96 + nt * 16 + li;
        bfrag[nt] = *reinterpret_cast<const s16x8*>(
            wsm + rb * 128 + (((kk * 4 + g) ^ (rb & 7)) << 4));
      }
#pragma unroll
      for (int mi = 0; mi < 4; ++mi) {
        int ra = wm * 64 + mi * 16 + li;
        s16x8 af = *reinterpret_cast<const s16x8*>(
            xs + ra * 128 + (((kk * 4 + g) ^ (ra & 7)) << 4));
#pragma unroll
        for (int nt = 0; nt < 6; ++nt)
          acc[mi][nt] = MFMA16(af, bfrag[nt], acc[mi][nt], 0, 0, 0);
      }
    }
  }

  // ---- epilogue: C/D layout col=l&15, row=(l>>4)*4+r ----
#pragma unroll
  for (int mi = 0; mi < 4; ++mi) {
    long m = mbase + wm * 64 + mi * 16 + g * 4;
#pragma unroll
    for (int nt = 0; nt < 6; ++nt) {
      int n = wn * 96 + nt * 16 + li;
      u16* base = (n < 64) ? Qo : (n < 128) ? Ko : Vo;
      int d = n & 63;
#pragma unroll
      for (int r = 0; r < 4; ++r)
        base[(m + r) * 64 + d] = f2bf(acc[mi][nt][r]);
    }
  }
}

// ---------------------------------------------------------------------------
// Kernel 2: causal attention, one batch per block, 8 waves of 64 lanes.
// Wave w handles 16-row q-tiles {w, 15-w} -> balanced 5 kv-chunks each.
// LDS: Ksm[256][64] swz (32KB) | Vt[64][256] swz (32KB) | P[wave][16][64] (16KB)
// ---------------------------------------------------------------------------
__global__ __launch_bounds__(512) void attn_kernel(
    const u16* __restrict__ Qw, const u16* __restrict__ Kw,
    const u16* __restrict__ Vw, float* __restrict__ out)
{
  __shared__ char smem[32768 + 32768 + 16384];
  char* Vt = smem + 32768;
  const int tid = threadIdx.x;
  const int l = tid & 63, w = tid >> 6;
  const int g = l >> 4, li = l & 15;
  const long base = (long)blockIdx.x * (256 * 64);

  // ---- stage K (row-major, swizzled) ----
#pragma unroll
  for (int i = 0; i < 4; ++i) {
    int id = tid + 512 * i;                // 2048 chunks
    int row = id >> 3, slot = id & 7;
    s16x8 v = *reinterpret_cast<const s16x8*>(Kw + base + row * 64 + slot * 8);
    *reinterpret_cast<s16x8*>(smem + row * 128 + ((slot ^ (row & 7)) << 4)) = v;
  }
  // ---- stage V transposed: Vt[d][kv], swizzled ----
#pragma unroll
  for (int i = 0; i < 4; ++i) {
    int id = tid + 512 * i;
    int row = id >> 3, slot = id & 7;
    s16x8 v = *reinterpret_cast<const s16x8*>(Vw + base + row * 64 + slot * 8);
#pragma unroll
    for (int j = 0; j < 8; ++j) {
      int d = slot * 8 + j;
      *reinterpret_cast<u16*>(Vt + d * 512 + ((row * 2) ^ ((d & 7) << 4))) =
          (u16)(unsigned short)v[j];
    }
  }
  __syncthreads();

  char* Pw = smem + 65536 + w * 2048;      // per-wave P buffer [16][64] bf16

  for (int half = 0; half < 2; ++half) {
    const int qt = half ? (15 - w) : w;
    s16x8 qf[2];
#pragma unroll
    for (int dk = 0; dk < 2; ++dk)
      qf[dk] = *reinterpret_cast<const s16x8*>(
          Qw + base + (qt * 16 + li) * 64 + dk * 32 + g * 8);

    f32x4 o[4];
    float m[4], lsum[4];
#pragma unroll
    for (int r = 0; r < 4; ++r) { m[r] = -1e30f; lsum[r] = 0.f; }
#pragma unroll
    for (int nd = 0; nd < 4; ++nd) o[nd] = (f32x4){0.f, 0.f, 0.f, 0.f};

    const int nc = (qt >> 2) + 1;
    for (int c = 0; c < nc; ++c) {
      // ---- S = Q K^T ----
      f32x4 s[4];
#pragma unroll
      for (int nj = 0; nj < 4; ++nj) s[nj] = (f32x4){0.f, 0.f, 0.f, 0.f};
#pragma unroll
      for (int dk = 0; dk < 2; ++dk) {
#pragma unroll
        for (int nj = 0; nj < 4; ++nj) {
          int rb = c * 64 + nj * 16 + li;
          s16x8 kf = *reinterpret_cast<const s16x8*>(
              smem + rb * 128 + (((dk * 4 + g) ^ (rb & 7)) << 4));
          s[nj] = MFMA16(qf[dk], kf, s[nj], 0, 0, 0);
        }
      }
      const bool last = (c == nc - 1);
      // ---- scale + causal mask ----
#pragma unroll
      for (int nj = 0; nj < 4; ++nj)
#pragma unroll
        for (int r = 0; r < 4; ++r) {
          float v = s[nj][r] * 0.125f;
          if (last && (c * 64 + nj * 16 + li) > (qt * 16 + g * 4 + r)) v = -1e30f;
          s[nj][r] = v;
        }
      // ---- online max ----
      float alpha[4];
#pragma unroll
      for (int r = 0; r < 4; ++r) {
        float pm = fmaxf(fmaxf(s[0][r], s[1][r]), fmaxf(s[2][r], s[3][r]));
        pm = fmaxf(pm, __shfl_xor(pm, 1));
        pm = fmaxf(pm, __shfl_xor(pm, 2));
        pm = fmaxf(pm, __shfl_xor(pm, 4));
        pm = fmaxf(pm, __shfl_xor(pm, 8));
        float mn = fmaxf(m[r], pm);
        alpha[r] = __expf(m[r] - mn);
        m[r] = mn;
      }
      // ---- P = exp(S-m), write bf16 to per-wave LDS (swizzled) ----
      float psum[4] = {0.f, 0.f, 0.f, 0.f};
#pragma unroll
      for (int nj = 0; nj < 4; ++nj)
#pragma unroll
        for (int r = 0; r < 4; ++r) {
          float p = __expf(s[nj][r] - m[r]);
          psum[r] += p;
          int row = g * 4 + r;
          *reinterpret_cast<u16*>(
              Pw + row * 128 + ((nj * 32 + li * 2) ^ ((row & 7) << 4))) = f2bf(p);
        }
#pragma unroll
      for (int r = 0; r < 4; ++r) {
        float ps = psum[r];
        ps += __shfl_xor(ps, 1);
        ps += __shfl_xor(ps, 2);
        ps += __shfl_xor(ps, 4);
        ps += __shfl_xor(ps, 8);
        lsum[r] = lsum[r] * alpha[r] + ps;
      }
#pragma unroll
      for (int nd = 0; nd < 4; ++nd)
#pragma unroll
        for (int r = 0; r < 4; ++r) o[nd][r] *= alpha[r];

      __asm__ volatile("s_waitcnt lgkmcnt(0)" ::: "memory");
      // ---- O += P V ----
      s16x8 pa[2];
#pragma unroll
      for (int kk = 0; kk < 2; ++kk)
        pa[kk] = *reinterpret_cast<const s16x8*>(
            Pw + li * 128 + (((kk * 4 + g) ^ (li & 7)) << 4));
#pragma unroll
      for (int nd = 0; nd < 4; ++nd) {
#pragma unroll
        for (int kk = 0; kk < 2; ++kk) {
          int d = nd * 16 + li;
          s16x8 vf = *reinterpret_cast<const s16x8*>(
              Vt + d * 512 + ((c * 128 + kk * 64 + g * 16) ^ ((d & 7) << 4)));
          o[nd] = MFMA16(pa[kk], vf, o[nd], 0, 0, 0);
        }
      }
    }
    // ---- epilogue ----
#pragma unroll
    for (int r = 0; r < 4; ++r) lsum[r] = 1.f / lsum[r];
#pragma unroll
    for (int nd = 0; nd < 4; ++nd)
#pragma unroll
      for (int r = 0; r < 4; ++r)
        out[base + (qt * 16 + g * 4 + r) * 64 + nd * 16 + li] = o[nd][r] * lsum[r];
  }
}

extern "C" void kernel_launch(void* const* d_in, const int* in_sizes, int n_in,
                              void* d_out, int out_size, void* d_ws, size_t ws_size,
                              hipStream_t stream) {
  const float* x  = (const float*)d_in[0];
  const float* WQ = (const float*)d_in[1];
  const float* WK = (const float*)d_in[2];
  const float* WV = (const float*)d_in[3];
  float* out = (float*)d_out;

  // workspace: Q | K | V bf16, each 512*256*64 elems = 16 MiB
  char* ws = (char*)d_ws;
  u16* Qo = (u16*)(ws);
  u16* Ko = (u16*)(ws + 16777216);
  u16* Vo = (u16*)(ws + 2 * 16777216);

  qkv_kernel<<<dim3(1024), dim3(256), 0, stream>>>(x, WQ, WK, WV, Qo, Ko, Vo);
  attn_kernel<<<dim3(512), dim3(512), 0, stream>>>(Qo, Ko, Vo, out);
}